// Round 13
// baseline (543.774 us; speedup 1.0000x reference)
//
#include <hip/hip_runtime.h>
#include <hip/hip_bf16.h>
#include <stdint.h>
#include <stddef.h>

typedef unsigned short u16;
typedef __bf16 bf16x8 __attribute__((ext_vector_type(8)));
typedef float f32x4 __attribute__((ext_vector_type(4)));
typedef float f32x16 __attribute__((ext_vector_type(16)));
typedef unsigned u32x2 __attribute__((ext_vector_type(2)));

#define NH 32
#define NKV 8
#define HD 128
#define QKV_N 6144
#define SEQ 2048

__device__ __forceinline__ u16 f2b(float x) {
  union { float f; unsigned u; } v; v.f = x;
  unsigned r = v.u + 0x7FFF + ((v.u >> 16) & 1);
  return (u16)(r >> 16);
}
__device__ __forceinline__ float b2f(u16 b) {
  union { float f; unsigned u; } v; v.u = ((unsigned)b) << 16;
  return v.f;
}
__device__ __forceinline__ void gload16(const void* g, void* l) {
  __builtin_amdgcn_global_load_lds((const __attribute__((address_space(1))) unsigned int*)g,
                                   (__attribute__((address_space(3))) unsigned int*)l, 16, 0, 0);
}
template <int N>
__device__ __forceinline__ void vmwait() {
  asm volatile("s_waitcnt vmcnt(%0)" ::"n"(N) : "memory");
}
__device__ __forceinline__ unsigned pk(float lo, float hi) {
  union { __bf16 h[2]; unsigned w; } u;
  u.h[0] = (__bf16)lo; u.h[1] = (__bf16)hi;
  return u.w;
}
__device__ __forceinline__ void plswap(unsigned& a, unsigned& b) {
  u32x2 r = __builtin_amdgcn_permlane32_swap(a, b, false, false);
  a = r.x; b = r.y;
}
__device__ __forceinline__ float pl_partner_max(float x) {
  unsigned u = __float_as_uint(x);
  u32x2 r = __builtin_amdgcn_permlane32_swap(u, u, false, false);
  return fmaxf(__uint_as_float(r.x), __uint_as_float(r.y));
}
__device__ __forceinline__ float pl_partner_sum(float x) {
  unsigned u = __float_as_uint(x);
  u32x2 r = __builtin_amdgcn_permlane32_swap(u, u, false, false);
  return __uint_as_float(r.x) + __uint_as_float(r.y);
}

// ---------------- cast fp32 -> bf16 (vectorized) ----------------
__global__ void cast_f32_bf16(const float* __restrict__ in, u16* __restrict__ out, int n) {
  int i = (blockIdx.x * blockDim.x + threadIdx.x) * 4;
  if (i >= n) return;
  float4 v = *(const float4*)&in[i];
  ushort4 o;
  o.x = f2b(v.x); o.y = f2b(v.y); o.z = f2b(v.z); o.w = f2b(v.w);
  *(ushort4*)&out[i] = o;
}

// ---------- cast + transpose: in [K][N] fp32 -> out [N][K] bf16 ----------
__global__ void cast_transpose(const float* __restrict__ in, u16* __restrict__ out, int K, int N) {
  __shared__ float t[32][33];
  int n0 = blockIdx.x * 32, k0 = blockIdx.y * 32;
  int tx = threadIdx.x, ty = threadIdx.y;  // (32,8)
#pragma unroll
  for (int i = 0; i < 4; ++i)
    t[ty + i * 8][tx] = in[(size_t)(k0 + ty + i * 8) * N + n0 + tx];
  __syncthreads();
#pragma unroll
  for (int i = 0; i < 4; ++i)
    out[(size_t)(n0 + ty + i * 8) * K + k0 + tx] = f2b(t[tx][ty + i * 8]);
}

__device__ __forceinline__ void storeC(float* C, size_t i, float v) { C[i] = v; }
__device__ __forceinline__ void storeC(u16* C, size_t i, float v) { C[i] = f2b(v); }

// ======== gemm_tri<BN>: BM=256, BK=64, A 3-buffered (stage t+2), B 2-buffered (stage t+1) ========
// ONE barrier per K-tile. Per tile τ:
//   stage B(τ+1)->bB[(τ+1)%2] (NI gloads); stage A(τ+2)->bA[(τ+2)%3] (4 gloads);
//   24 ds_read_b128 (A-lo, B, A-hi); MFMA both halves (compiler lgkmcnt interleave);
//   vmwait(4) [drains A(τ+1) issued τ-1 AND B(τ+1) issued this tile]; BAR.
// WAR safety (architectural, not timing): stages never touch buffers read in tile τ or τ+1.
//   A buf (τ+2)%3 last read at τ-1; every wave's τ-1 reads drained by its own lgkmcnt before
//   its MFMA (pinned pre-barrier by dependency + sched_barrier), so all reads complete before
//   any wave passes BAR(τ-1); overwriting stage issues after that BAR. Same for B (2-buf, 1-ahead).
// RAW: vmwait(4) before BAR is per-wave but every wave drains ITS OWN slice, and BAR joins them.
// Queue invariant entering τ: [A(τ+1)]=4. Issue B(τ+1),A(τ+2) -> wait(4) leaves [A(τ+2)]=4.
#define TMM(h, X0, X1)                                                                         \
  _Pragma("unroll") for (int mi = 0; mi < 4; ++mi)                                             \
    _Pragma("unroll") for (int ni = 0; ni < NI; ++ni)                                          \
      acc[h][mi][ni] = __builtin_amdgcn_mfma_f32_16x16x32_bf16(X0[mi], b0[ni], acc[h][mi][ni], 0, 0, 0); \
  _Pragma("unroll") for (int mi = 0; mi < 4; ++mi)                                             \
    _Pragma("unroll") for (int ni = 0; ni < NI; ++ni)                                          \
      acc[h][mi][ni] = __builtin_amdgcn_mfma_f32_16x16x32_bf16(X1[mi], b1[ni], acc[h][mi][ni], 0, 0, 0);

#define KTT(RA, RB2, SA, SB2, SGA, SGB, VM)                                                    \
  {                                                                                            \
    if (SGB) {                                                                                 \
      gload16(pB0, dB0 + (SB2) * BS); gload16(pB1, dB1 + (SB2) * BS);                          \
      pB0 += 64; pB1 += 64;                                                                    \
      if (NI >= 3) { gload16(pB2, dB2 + (SB2) * BS); pB2 += 64; }                              \
    }                                                                                          \
    if (SGA) {                                                                                 \
      gload16(pA0, dA0 + (SA) * 16384); gload16(pA1, dA1 + (SA) * 16384);                      \
      gload16(pA2, dA2 + (SA) * 16384); gload16(pA3, dA3 + (SA) * 16384);                      \
      pA0 += 64; pA1 += 64; pA2 += 64; pA3 += 64;                                              \
    }                                                                                          \
    bf16x8 al0[4], al1[4], ah0[4], ah1[4], b0[NI], b1[NI];                                     \
    _Pragma("unroll") for (int mi = 0; mi < 4; ++mi) {                                         \
      al0[mi] = *(const bf16x8*)(rA0 + (RA) * 16384 + mi * 1024);                              \
      al1[mi] = *(const bf16x8*)(rA1 + (RA) * 16384 + mi * 1024);                              \
    }                                                                                          \
    _Pragma("unroll") for (int ni = 0; ni < NI; ++ni) {                                        \
      b0[ni] = *(const bf16x8*)(rB0 + (RB2) * BS + ni * 1024);                                 \
      b1[ni] = *(const bf16x8*)(rB1 + (RB2) * BS + ni * 1024);                                 \
    }                                                                                          \
    _Pragma("unroll") for (int mi = 0; mi < 4; ++mi) {                                         \
      ah0[mi] = *(const bf16x8*)(rA0 + (RA) * 16384 + 8192 + mi * 1024);                       \
      ah1[mi] = *(const bf16x8*)(rA1 + (RA) * 16384 + 8192 + mi * 1024);                       \
    }                                                                                          \
    __builtin_amdgcn_s_setprio(1);                                                             \
    TMM(0, al0, al1)                                                                           \
    TMM(1, ah0, ah1)                                                                           \
    __builtin_amdgcn_s_setprio(0);                                                             \
    __builtin_amdgcn_sched_barrier(0);                                                         \
    if ((VM) == 2) vmwait<4>();                                                                \
    else if ((VM) == 1) vmwait<0>();                                                           \
    __builtin_amdgcn_s_barrier();                                                              \
  }

template <int BN, typename OutT>
__global__ __launch_bounds__(512, 2) void gemm_tri(const u16* __restrict__ A, const u16* __restrict__ Bt,
                                                   OutT* __restrict__ C, int M, int N, int K) {
  constexpr int NI = BN / 64;      // B frags per wave (cols/wave = BN/4)
  constexpr int BS = BN * 64;      // B buffer stride, u16 elems
  __shared__ __align__(16) u16 sA[3 * 16384];  // 3 x 32 KiB
  __shared__ __align__(16) u16 sB[2 * BS];     // 2 x (BN*64*2) B
  const int nbx = N / BN;
  const int nwg = (M >> 8) * nbx;
  const int cpx = nwg >> 3;  // nwg % 8 == 0 (512 for both uses)
  const int wg = ((int)blockIdx.x & 7) * cpx + ((int)blockIdx.x >> 3);
  const int row0 = (wg / nbx) << 8, col0 = (wg % nbx) * BN;
  const int tid = threadIdx.x, w = tid >> 6, lane = tid & 63;
  const int wm = w >> 2, wn = w & 3;
  const int lq = lane & 15, lh = lane >> 4, x7 = lq & 7;
  const int o0 = (lh ^ x7) << 3, o1 = ((4 + lh) ^ x7) << 3;

  const int rr = tid >> 3;
  const int swz = ((tid & 7) ^ (rr & 7)) << 3;
  const u16* pA0 = A + (size_t)(row0 + rr) * K + swz;
  const u16* pA1 = A + (size_t)(row0 + 64 + rr) * K + swz;
  const u16* pA2 = A + (size_t)(row0 + 128 + rr) * K + swz;
  const u16* pA3 = A + (size_t)(row0 + 192 + rr) * K + swz;
  const u16* pB0 = Bt + (size_t)(col0 + rr) * K + swz;
  const u16* pB1 = Bt + (size_t)(col0 + 64 + rr) * K + swz;
  const u16* pB2 = Bt + (size_t)(col0 + 128 + rr) * K + swz;  // used when NI>=3
  u16* dA0 = sA + w * 512;
  u16* dA1 = sA + 4096 + w * 512;
  u16* dA2 = sA + 8192 + w * 512;
  u16* dA3 = sA + 12288 + w * 512;
  u16* dB0 = sB + w * 512;
  u16* dB1 = sB + 4096 + w * 512;
  u16* dB2 = sB + 8192 + w * 512;
  const u16* rA0 = sA + (wm * 64 + lq) * 64 + o0;
  const u16* rA1 = sA + (wm * 64 + lq) * 64 + o1;
  const u16* rB0 = sB + (wn * (BN / 4) + lq) * 64 + o0;
  const u16* rB1 = sB + (wn * (BN / 4) + lq) * 64 + o1;

  f32x4 acc[2][4][NI] = {};

  // prologue: A(0)->bA0, B(0)->bB0, A(1)->bA1; drain A0,B0; leaves [A(1)]=4
  gload16(pA0, dA0); gload16(pA1, dA1); gload16(pA2, dA2); gload16(pA3, dA3);
  pA0 += 64; pA1 += 64; pA2 += 64; pA3 += 64;
  gload16(pB0, dB0); gload16(pB1, dB1);
  pB0 += 64; pB1 += 64;
  if (NI >= 3) { gload16(pB2, dB2); pB2 += 64; }
  gload16(pA0, dA0 + 16384); gload16(pA1, dA1 + 16384);
  gload16(pA2, dA2 + 16384); gload16(pA3, dA3 + 16384);
  pA0 += 64; pA1 += 64; pA2 += 64; pA3 += 64;
  vmwait<4>();
  __builtin_amdgcn_s_barrier();

  // K = 4096 -> nt = 64 tiles. Period lcm(3,2)=6, 10 iters = tiles 0..59.
  for (int it = 0; it < 10; ++it) {
    KTT(0, 0, 2, 1, 1, 1, 2)
    KTT(1, 1, 0, 0, 1, 1, 2)
    KTT(2, 0, 1, 1, 1, 1, 2)
    KTT(0, 1, 2, 0, 1, 1, 2)
    KTT(1, 0, 0, 1, 1, 1, 2)
    KTT(2, 1, 1, 0, 1, 1, 2)
  }
  KTT(0, 0, 2, 1, 1, 1, 2)  // t60: stage A62->bA2, B61->bB1
  KTT(1, 1, 0, 0, 1, 1, 2)  // t61: stage A63->bA0, B62->bB0
  KTT(2, 0, 0, 1, 0, 1, 1)  // t62: stage B63->bB1 only; vmwait(0)
  KTT(0, 1, 0, 0, 0, 0, 0)  // t63

#pragma unroll
  for (int ah = 0; ah < 2; ++ah)
#pragma unroll
    for (int mi = 0; mi < 4; ++mi)
#pragma unroll
      for (int ni = 0; ni < NI; ++ni)
#pragma unroll
        for (int j = 0; j < 4; ++j) {
          const int row = row0 + ah * 128 + wm * 64 + mi * 16 + lh * 4 + j;
          const int col = col0 + wn * (BN / 4) + ni * 16 + lq;
          storeC(C, (size_t)row * N + col, acc[ah][mi][ni][j]);
        }
}

// ---------------- RoPE (NeoX), in-place on qkv; vectorized ushort4 I/O ----------------
__global__ void rope_kernel(u16* __restrict__ qkv, const int* __restrict__ pos, float qscale) {
  __shared__ float cs[64], sn[64];
  const int row = blockIdx.x;
  const int tid = threadIdx.x;
  if (tid < 64) {
    float p = (float)pos[row];
    float inv = exp2f(-(float)tid * 0.20762050593046f);
    float a = p * inv;
    cs[tid] = cosf(a);
    sn[tid] = sinf(a);
  }
  __syncthreads();
  const size_t base = (size_t)row * QKV_N;
  for (int i = tid; i < 40 * 16; i += 256) {  // 40 heads x 16 d-quads
    const int h = i >> 4, dq = (i & 15) * 4;
    const size_t o = base + h * 128 + dq;
    ushort4 v1 = *(const ushort4*)&qkv[o];
    ushort4 v2 = *(const ushort4*)&qkv[o + 64];
    const float sc = (h < NH) ? qscale : 1.0f;
    ushort4 r1, r2;
    {
      float x1 = b2f(v1.x), x2 = b2f(v2.x), c = cs[dq], s = sn[dq];
      r1.x = f2b((x1 * c - x2 * s) * sc); r2.x = f2b((x2 * c + x1 * s) * sc);
    }
    {
      float x1 = b2f(v1.y), x2 = b2f(v2.y), c = cs[dq + 1], s = sn[dq + 1];
      r1.y = f2b((x1 * c - x2 * s) * sc); r2.y = f2b((x2 * c + x1 * s) * sc);
    }
    {
      float x1 = b2f(v1.z), x2 = b2f(v2.z), c = cs[dq + 2], s = sn[dq + 2];
      r1.z = f2b((x1 * c - x2 * s) * sc); r2.z = f2b((x2 * c + x1 * s) * sc);
    }
    {
      float x1 = b2f(v1.w), x2 = b2f(v2.w), c = cs[dq + 3], s = sn[dq + 3];
      r1.w = f2b((x1 * c - x2 * s) * sc); r2.w = f2b((x2 * c + x1 * s) * sc);
    }
    *(ushort4*)&qkv[o] = r1;
    *(ushort4*)&qkv[o + 64] = r2;
  }
}

// ---------------- V transpose: qkv v-section -> vt[(b*8+kvh)*128 + d][2048] ----------------
__global__ void v_transpose(const u16* __restrict__ qkv, u16* __restrict__ vt) {
  __shared__ u16 t[32][33];
  const int b = blockIdx.z >> 3, kvh = blockIdx.z & 7;
  const int s0 = blockIdx.x * 32, d0 = blockIdx.y * 32;
  const int tx = threadIdx.x, ty = threadIdx.y;
#pragma unroll
  for (int i = 0; i < 4; ++i)
    t[ty + i * 8][tx] = qkv[(size_t)(b * SEQ + s0 + ty + i * 8) * QKV_N + 5120 + kvh * 128 + d0 + tx];
  __syncthreads();
#pragma unroll
  for (int i = 0; i < 4; ++i)
    vt[(size_t)((b * NKV + kvh) * HD + d0 + ty + i * 8) * SEQ + s0 + tx] = t[tx][ty + i * 8];
}

// ---------------- Flash attention: 8 waves x 32 q-rows, 32x32x16 MFMA, swapped QK^T ----------------
__global__ __launch_bounds__(512, 2) void attn_kernel(const u16* __restrict__ qkv, const u16* __restrict__ vt,
                                                      u16* __restrict__ attn) {
  __shared__ __align__(16) u16 sK[2][64 * 128];   // [kv][d]
  __shared__ __align__(16) u16 sV[2][128 * 64];   // [d][kv]
  const int b = blockIdx.z, h = blockIdx.y;
  const int qt = (b == 0) ? blockIdx.x : 7 - blockIdx.x;  // anti-correlated pairing for balance
  const int kvh = h >> 2;
  const int qb = qt * 256;
  const int tid = threadIdx.x, w = tid >> 6, lane = tid & 63;
  const int lq = lane & 31, hi = lane >> 5, x7 = lane & 7;
  const int qw = qb + (w << 5);
  const int qa = qw + lq;
  const int nt = 4 * (qt + 1);

  auto stage = [&](int buf, int kt) {
    const int k0 = kt * 64;
#pragma unroll
    for (int c = 0; c < 2; ++c) {
      const int g = c * 512 + tid;
      const int r = g >> 4, gc = g & 15;
      const int gs = gc ^ (r & 7);
      gload16(qkv + (size_t)(b * SEQ + k0 + r) * QKV_N + 4096 + kvh * 128 + gs * 8,
              &sK[buf][(c * 512 + (w << 6)) * 8]);
    }
#pragma unroll
    for (int c = 0; c < 2; ++c) {
      const int g = c * 512 + tid;
      const int r = g >> 3, gc = g & 7;
      const int gs = gc ^ (r & 7);
      gload16(vt + (size_t)((b * NKV + kvh) * HD + r) * SEQ + k0 + gs * 8,
              &sV[buf][(c * 512 + (w << 6)) * 8]);
    }
  };

  stage(0, 0);
  bf16x8 qf[8];
#pragma unroll
  for (int ks = 0; ks < 8; ++ks)
    qf[ks] = *(const bf16x8*)&qkv[(size_t)(b * SEQ + qw + lq) * QKV_N + h * 128 + ks * 16 + 8 * hi];

  f32x16 o[4] = {};
  float mreg = -1e30f, lreg = 0.f;

  asm volatile("s_waitcnt vmcnt(0)" ::: "memory");
  __builtin_amdgcn_s_barrier();

  for (int kt = 0; kt < nt; ++kt) {
    const int cur = kt & 1;
    const int k0 = kt * 64;
    if (kt + 1 < nt) {
      stage(cur ^ 1, kt + 1);
      asm volatile("s_waitcnt vmcnt(4)" ::: "memory");
    } else {
      asm volatile("s_waitcnt vmcnt(0)" ::: "memory");
    }
    __builtin_amdgcn_s_barrier();

    if (k0 <= qw + 31) {  // wave-active (causal skip)
      const u16* sk = sK[cur];
      f32x16 st0 = {}, st1 = {};
      __builtin_amdgcn_s_setprio(1);
#pragma unroll
      for (int ks = 0; ks < 8; ++ks) {
        const int g = ((2 * ks + hi) ^ x7) * 8;
        bf16x8 kf0 = *(const bf16x8*)&sk[lq * 128 + g];
        bf16x8 kf1 = *(const bf16x8*)&sk[(32 + lq) * 128 + g];
        st0 = __builtin_amdgcn_mfma_f32_32x32x16_bf16(kf0, qf[ks], st0, 0, 0, 0);
        st1 = __builtin_amdgcn_mfma_f32_32x32x16_bf16(kf1, qf[ks], st1, 0, 0, 0);
      }
      __builtin_amdgcn_s_setprio(0);
      if (k0 + 63 > qw) {
#pragma unroll
        for (int r = 0; r < 16; ++r) {
          const int cr = (r & 3) + 8 * (r >> 2) + 4 * hi;
          st0[r] = (k0 + cr <= qa) ? st0[r] : -1e30f;
          st1[r] = (k0 + 32 + cr <= qa) ? st1[r] : -1e30f;
        }
      }
      float a8[8];
#pragma unroll
      for (int r = 0; r < 8; ++r)
        a8[r] = fmaxf(fmaxf(st0[r], st0[r + 8]), fmaxf(st1[r], st1[r + 8]));
#pragma unroll
      for (int s = 4; s; s >>= 1)
#pragma unroll
        for (int r = 0; r < s; ++r) a8[r] = fmaxf(a8[r], a8[r + s]);
      const float pm = pl_partner_max(a8[0]);
      if (!__all(pm <= mreg + 8.f)) {
        const float mn = fmaxf(mreg, pm);
        const float al = exp2f(mreg - mn);
        lreg *= al;
        mreg = mn;
#pragma unroll
        for (int r = 0; r < 16; ++r) {
          const int cr = (r & 3) + 8 * (r >> 2) + 4 * hi;
          const float ar = __shfl(al, cr, 64);
#pragma unroll
          for (int dn = 0; dn < 4; ++dn) o[dn][r] *= ar;
        }
      }
#pragma unroll
      for (int r = 0; r < 16; ++r) {
        st0[r] = exp2f(st0[r] - mreg);
        st1[r] = exp2f(st1[r] - mreg);
      }
      float s8[8];
#pragma unroll
      for (int r = 0; r < 8; ++r)
        s8[r] = (st0[r] + st0[r + 8]) + (st1[r] + st1[r + 8]);
#pragma unroll
      for (int s = 4; s; s >>= 1)
#pragma unroll
        for (int r = 0; r < s; ++r) s8[r] += s8[r + s];
      lreg += pl_partner_sum(s8[0]);
      union U8 { unsigned w[4]; bf16x8 v; };
      U8 pa[4];
#define PACKFRAG(F, P0, P1, P2, P3, P4, P5, P6, P7)                   \
      {                                                               \
        unsigned a0 = pk(P0, P1), a1 = pk(P2, P3);                    \
        unsigned b0 = pk(P4, P5), b1 = pk(P6, P7);                    \
        plswap(a0, b0); plswap(a1, b1);                               \
        pa[F].w[0] = a0; pa[F].w[1] = a1; pa[F].w[2] = b0; pa[F].w[3] = b1; \
      }
      PACKFRAG(0, st0[0], st0[1], st0[2], st0[3], st0[4], st0[5], st0[6], st0[7])
      PACKFRAG(1, st0[8], st0[9], st0[10], st0[11], st0[12], st0[13], st0[14], st0[15])
      PACKFRAG(2, st1[0], st1[1], st1[2], st1[3], st1[4], st1[5], st1[6], st1[7])
      PACKFRAG(3, st1[8], st1[9], st1[10], st1[11], st1[12], st1[13], st1[14], st1[15])
#undef PACKFRAG
      const u16* sv = sV[cur];
      __builtin_amdgcn_s_setprio(1);
#pragma unroll
      for (int dn = 0; dn < 4; ++dn) {
#pragma unroll
        for (int ks = 0; ks < 4; ++ks) {
          bf16x8 vf = *(const bf16x8*)&sv[(dn * 32 + lq) * 64 + (((2 * ks + hi) ^ x7)) * 8];
          o[dn] = __builtin_amdgcn_mfma_f32_32x32x16_bf16(pa[ks].v, vf, o[dn], 0, 0, 0);
        }
      }
      __builtin_amdgcn_s_setprio(0);
    }
    __builtin_amdgcn_s_barrier();
  }

  const float inv = 1.0f / lreg;
#pragma unroll
  for (int r = 0; r < 16; ++r) {
    const int cr = (r & 3) + 8 * (r >> 2) + 4 * hi;
    const float fr = __shfl(inv, cr, 64);
    const size_t row = (size_t)(b * SEQ + qw + cr);
#pragma unroll
    for (int dn = 0; dn < 4; ++dn)
      attn[row * 4096 + h * 128 + dn * 32 + lq] = f2b(o[dn][r] * fr);
  }
}

extern "C" void kernel_launch(void* const* d_in, const int* in_sizes, int n_in,
                              void* d_out, int out_size, void* d_ws, size_t ws_size,
                              hipStream_t stream) {
  const float* hs = (const float*)d_in[0];
  const int* pos = (const int*)d_in[1];
  const float* w_qkv = (const float*)d_in[2];
  const float* w_o = (const float*)d_in[3];
  float* out = (float*)d_out;
  char* ws = (char*)d_ws;

  u16* hid = (u16*)ws;                        // 4096*4096 bf16 = 32 MiB
  u16* attnb = hid;                           // reused after qkv GEMM consumes hid
  u16* wT = (u16*)(ws + 33554432);            // up to 6144*4096 bf16 = 48 MiB
  u16* qkv = (u16*)(ws + 83886080);           // 4096*6144 bf16 = 48 MiB
  u16* vt = (u16*)(ws + 134217728);           // 2*8*128*2048 bf16 = 8 MiB

  const float qscale = 0.12751744f;  // (1/sqrt(128)) * log2(e)

  cast_f32_bf16<<<16384, 256, 0, stream>>>(hs, hid, 4096 * 4096);
  cast_transpose<<<dim3(192, 128), dim3(32, 8), 0, stream>>>(w_qkv, wT, 4096, QKV_N);
  gemm_tri<192, u16><<<512, 512, 0, stream>>>(hid, wT, qkv, 4096, QKV_N, 4096);
  rope_kernel<<<4096, 256, 0, stream>>>(qkv, pos, qscale);
  v_transpose<<<dim3(64, 4, 16), dim3(32, 8), 0, stream>>>(qkv, vt);
  cast_transpose<<<dim3(128, 128), dim3(32, 8), 0, stream>>>(w_o, wT, 4096, 4096);
  attn_kernel<<<dim3(8, 32, 2), 512, 0, stream>>>(qkv, vt, attnb);
  gemm_tri<128, float><<<512, 512, 0, stream>>>(attnb, wT, out, 4096, 4096, 4096);
}

// Round 14
// 517.639 us; speedup vs baseline: 1.0505x; 1.0505x over previous
//
#include <hip/hip_runtime.h>
#include <hip/hip_bf16.h>
#include <stdint.h>
#include <stddef.h>

typedef unsigned short u16;
typedef __bf16 bf16x8 __attribute__((ext_vector_type(8)));
typedef float f32x4 __attribute__((ext_vector_type(4)));
typedef float f32x16 __attribute__((ext_vector_type(16)));
typedef unsigned u32x2 __attribute__((ext_vector_type(2)));

#define NH 32
#define NKV 8
#define HD 128
#define QKV_N 6144
#define SEQ 2048

__device__ __forceinline__ u16 f2b(float x) {
  union { float f; unsigned u; } v; v.f = x;
  unsigned r = v.u + 0x7FFF + ((v.u >> 16) & 1);
  return (u16)(r >> 16);
}
__device__ __forceinline__ float b2f(u16 b) {
  union { float f; unsigned u; } v; v.u = ((unsigned)b) << 16;
  return v.f;
}
__device__ __forceinline__ void gload16(const void* g, void* l) {
  __builtin_amdgcn_global_load_lds((const __attribute__((address_space(1))) unsigned int*)g,
                                   (__attribute__((address_space(3))) unsigned int*)l, 16, 0, 0);
}
template <int N>
__device__ __forceinline__ void vmwait() {
  asm volatile("s_waitcnt vmcnt(%0)" ::"n"(N) : "memory");
}
__device__ __forceinline__ unsigned pk(float lo, float hi) {
  union { __bf16 h[2]; unsigned w; } u;
  u.h[0] = (__bf16)lo; u.h[1] = (__bf16)hi;
  return u.w;
}
__device__ __forceinline__ void plswap(unsigned& a, unsigned& b) {
  u32x2 r = __builtin_amdgcn_permlane32_swap(a, b, false, false);
  a = r.x; b = r.y;
}
__device__ __forceinline__ float pl_partner_max(float x) {
  unsigned u = __float_as_uint(x);
  u32x2 r = __builtin_amdgcn_permlane32_swap(u, u, false, false);
  return fmaxf(__uint_as_float(r.x), __uint_as_float(r.y));
}
__device__ __forceinline__ float pl_partner_sum(float x) {
  unsigned u = __float_as_uint(x);
  u32x2 r = __builtin_amdgcn_permlane32_swap(u, u, false, false);
  return __uint_as_float(r.x) + __uint_as_float(r.y);
}

// ---------------- cast fp32 -> bf16 (vectorized) ----------------
__global__ void cast_f32_bf16(const float* __restrict__ in, u16* __restrict__ out, int n) {
  int i = (blockIdx.x * blockDim.x + threadIdx.x) * 4;
  if (i >= n) return;
  float4 v = *(const float4*)&in[i];
  ushort4 o;
  o.x = f2b(v.x); o.y = f2b(v.y); o.z = f2b(v.z); o.w = f2b(v.w);
  *(ushort4*)&out[i] = o;
}

// ---------- cast + transpose: in [K][N] fp32 -> out [N][K] bf16 ----------
__global__ void cast_transpose(const float* __restrict__ in, u16* __restrict__ out, int K, int N) {
  __shared__ float t[32][33];
  int n0 = blockIdx.x * 32, k0 = blockIdx.y * 32;
  int tx = threadIdx.x, ty = threadIdx.y;  // (32,8)
#pragma unroll
  for (int i = 0; i < 4; ++i)
    t[ty + i * 8][tx] = in[(size_t)(k0 + ty + i * 8) * N + n0 + tx];
  __syncthreads();
#pragma unroll
  for (int i = 0; i < 4; ++i)
    out[(size_t)(n0 + ty + i * 8) * K + k0 + tx] = f2b(t[tx][ty + i * 8]);
}

__device__ __forceinline__ void storeC(float* C, size_t i, float v) { C[i] = v; }
__device__ __forceinline__ void storeC(u16* C, size_t i, float v) { C[i] = f2b(v); }

// ======================= gemm256 (KT256 ladder; o-proj, 256 blocks = 1/CU) =======================
#define MFMA16(q, A0, A1, B0, B1)                                                              \
  {                                                                                            \
    _Pragma("unroll") for (int mi = 0; mi < 4; ++mi)                                           \
      _Pragma("unroll") for (int ni = 0; ni < 2; ++ni)                                         \
        acc[q][mi][ni] = __builtin_amdgcn_mfma_f32_16x16x32_bf16(A0[mi], B0[ni], acc[q][mi][ni], 0, 0, 0); \
    _Pragma("unroll") for (int mi = 0; mi < 4; ++mi)                                           \
      _Pragma("unroll") for (int ni = 0; ni < 2; ++ni)                                         \
        acc[q][mi][ni] = __builtin_amdgcn_mfma_f32_16x16x32_bf16(A1[mi], B1[ni], acc[q][mi][ni], 0, 0, 0); \
  }

#define KT256(NOFF, SGHI, SGLO, HASV0, HASV1, VM1)                                             \
  {                                                                                            \
    bf16x8 a0[4], a1[4], bl0[2], bl1[2], bh0[2], bh1[2];                                       \
    _Pragma("unroll") for (int mi = 0; mi < 4; ++mi) {                                         \
      a0[mi] = *(const bf16x8*)(rA0 + (NOFF) + mi * 1024);                                     \
      a1[mi] = *(const bf16x8*)(rA1 + (NOFF) + mi * 1024);                                     \
    }                                                                                          \
    _Pragma("unroll") for (int ni = 0; ni < 2; ++ni) {                                         \
      bl0[ni] = *(const bf16x8*)(rB0 + (NOFF) + ni * 1024);                                    \
      bl1[ni] = *(const bf16x8*)(rB1 + (NOFF) + ni * 1024);                                    \
      bh0[ni] = *(const bf16x8*)(rB0 + (NOFF) + 8192 + ni * 1024);                             \
      bh1[ni] = *(const bf16x8*)(rB1 + (NOFF) + 8192 + ni * 1024);                             \
    }                                                                                          \
    if (SGHI) {                                                                                \
      gload16(pAhi0, dAhi0 + ((NOFF) ^ 16384)); gload16(pAhi1, dAhi1 + ((NOFF) ^ 16384));      \
      pAhi0 += 64; pAhi1 += 64;                                                                \
      gload16(pBlo0, dBlo0 + ((NOFF) ^ 16384)); gload16(pBlo1, dBlo1 + ((NOFF) ^ 16384));      \
      gload16(pBhi0, dBhi0 + ((NOFF) ^ 16384)); gload16(pBhi1, dBhi1 + ((NOFF) ^ 16384));      \
      pBlo0 += 64; pBlo1 += 64; pBhi0 += 64; pBhi1 += 64;                                      \
    }                                                                                          \
    __builtin_amdgcn_s_barrier();                                                              \
    __builtin_amdgcn_s_setprio(1);                                                             \
    MFMA16(0, a0, a1, bl0, bl1)                                                                \
    MFMA16(1, a0, a1, bh0, bh1)                                                                \
    __builtin_amdgcn_s_setprio(0);                                                             \
    __builtin_amdgcn_sched_barrier(0);                                                         \
    if (HASV0) vmwait<8>();                                                                    \
    __builtin_amdgcn_s_barrier();                                                              \
    _Pragma("unroll") for (int mi = 0; mi < 4; ++mi) {                                         \
      a0[mi] = *(const bf16x8*)(rA0 + (NOFF) + 8192 + mi * 1024);                              \
      a1[mi] = *(const bf16x8*)(rA1 + (NOFF) + 8192 + mi * 1024);                              \
    }                                                                                          \
    if (SGLO) {                                                                                \
      gload16(pAlo0, dAlo0 + (NOFF)); gload16(pAlo1, dAlo1 + (NOFF));                          \
      pAlo0 += 64; pAlo1 += 64;                                                                \
    }                                                                                          \
    __builtin_amdgcn_s_barrier();                                                              \
    __builtin_amdgcn_s_setprio(1);                                                             \
    MFMA16(2, a0, a1, bl0, bl1)                                                                \
    MFMA16(3, a0, a1, bh0, bh1)                                                                \
    __builtin_amdgcn_s_setprio(0);                                                             \
    __builtin_amdgcn_sched_barrier(0);                                                         \
    if (HASV1) vmwait<VM1>();                                                                  \
    __builtin_amdgcn_s_barrier();                                                              \
  }

template <typename OutT>
__global__ __launch_bounds__(512, 2) void gemm256(const u16* __restrict__ A, const u16* __restrict__ Bt,
                                                  OutT* __restrict__ C, int M, int N, int K) {
  __shared__ __align__(16) u16 sA[2 * 16384];
  __shared__ __align__(16) u16 sB[2 * 16384];
  const int nbx = N >> 8;
  const int nwg = (M >> 8) * nbx;
  const int cpx = nwg >> 3;
  const int wg = ((int)blockIdx.x & 7) * cpx + ((int)blockIdx.x >> 3);
  const int row0 = (wg / nbx) << 8, col0 = (wg % nbx) << 8;
  const int tid = threadIdx.x, w = tid >> 6, lane = tid & 63;
  const int wm = w >> 2, wn = w & 3;
  const int lq = lane & 15, lh = lane >> 4, x7 = lq & 7;
  const int o0 = (lh ^ x7) << 3, o1 = ((4 + lh) ^ x7) << 3;
  const int nt = K >> 6;

  const int rr = tid >> 3;
  const int swz = ((tid & 7) ^ (rr & 7)) << 3;
  const u16* pAlo0 = A + (size_t)(row0 + rr) * K + swz;
  const u16* pAlo1 = A + (size_t)(row0 + 64 + rr) * K + swz;
  const u16* pAhi0 = A + (size_t)(row0 + 128 + rr) * K + swz;
  const u16* pAhi1 = A + (size_t)(row0 + 192 + rr) * K + swz;
  const u16* pBlo0 = Bt + (size_t)(col0 + rr) * K + swz;
  const u16* pBlo1 = Bt + (size_t)(col0 + 64 + rr) * K + swz;
  const u16* pBhi0 = Bt + (size_t)(col0 + 128 + rr) * K + swz;
  const u16* pBhi1 = Bt + (size_t)(col0 + 192 + rr) * K + swz;
  u16* dAlo0 = sA + w * 512;
  u16* dAlo1 = sA + 4096 + w * 512;
  u16* dAhi0 = sA + 8192 + w * 512;
  u16* dAhi1 = sA + 12288 + w * 512;
  u16* dBlo0 = sB + w * 512;
  u16* dBlo1 = sB + 4096 + w * 512;
  u16* dBhi0 = sB + 8192 + w * 512;
  u16* dBhi1 = sB + 12288 + w * 512;
  const u16* rA0 = sA + (wm * 64 + lq) * 64 + o0;
  const u16* rA1 = sA + (wm * 64 + lq) * 64 + o1;
  const u16* rB0 = sB + (wn * 32 + lq) * 64 + o0;
  const u16* rB1 = sB + (wn * 32 + lq) * 64 + o1;

  f32x4 acc[4][4][2] = {};

  gload16(pAlo0, dAlo0); gload16(pAlo1, dAlo1); pAlo0 += 64; pAlo1 += 64;
  gload16(pBlo0, dBlo0); gload16(pBlo1, dBlo1); pBlo0 += 64; pBlo1 += 64;
  gload16(pBhi0, dBhi0); gload16(pBhi1, dBhi1); pBhi0 += 64; pBhi1 += 64;
  gload16(pAhi0, dAhi0); gload16(pAhi1, dAhi1); pAhi0 += 64; pAhi1 += 64;
  gload16(pAlo0, dAlo0 + 16384); gload16(pAlo1, dAlo1 + 16384); pAlo0 += 64; pAlo1 += 64;
  vmwait<4>();  // A-lo(0), B(0) landed; leaves [A-hi(0)2, A-lo(1)2]
  __builtin_amdgcn_s_barrier();

  for (int t = 0; t < nt - 2; t += 2) {
    KT256(0, 1, 1, 1, 1, 2)
    KT256(16384, 1, 1, 1, 1, 2)
  }
  KT256(0, 1, 0, 1, 1, 0)      // t = nt-2
  KT256(16384, 0, 0, 0, 0, 0)  // t = nt-1

#pragma unroll
  for (int q = 0; q < 4; ++q) {
    const int ah = q >> 1, bh2 = q & 1;
#pragma unroll
    for (int mi = 0; mi < 4; ++mi)
#pragma unroll
      for (int ni = 0; ni < 2; ++ni)
#pragma unroll
        for (int j = 0; j < 4; ++j) {
          const int row = row0 + ah * 128 + wm * 64 + mi * 16 + lh * 4 + j;
          const int col = col0 + bh2 * 128 + wn * 32 + ni * 16 + lq;
          storeC(C, (size_t)row * N + col, acc[q][mi][ni][j]);
        }
  }
}

// ======================= gemm192: BM=256, BN=192, dbuf (qkv; 512 blocks, 2 balanced rounds) =======================
#define MM24(q, A0, A1)                                                                        \
  {                                                                                            \
    _Pragma("unroll") for (int mi = 0; mi < 4; ++mi)                                           \
      _Pragma("unroll") for (int ni = 0; ni < 3; ++ni)                                         \
        acc[q][mi][ni] = __builtin_amdgcn_mfma_f32_16x16x32_bf16(A0[mi], b0[ni], acc[q][mi][ni], 0, 0, 0); \
    _Pragma("unroll") for (int mi = 0; mi < 4; ++mi)                                           \
      _Pragma("unroll") for (int ni = 0; ni < 3; ++ni)                                         \
        acc[q][mi][ni] = __builtin_amdgcn_mfma_f32_16x16x32_bf16(A1[mi], b1[ni], acc[q][mi][ni], 0, 0, 0); \
  }

#define KT192(NA, NB, SGHI, SGLO, HASV0, HASV1, VM1)                                           \
  {                                                                                            \
    bf16x8 a0[4], a1[4], b0[3], b1[3];                                                         \
    _Pragma("unroll") for (int mi = 0; mi < 4; ++mi) {                                         \
      a0[mi] = *(const bf16x8*)(rA0 + (NA) + mi * 1024);                                       \
      a1[mi] = *(const bf16x8*)(rA1 + (NA) + mi * 1024);                                       \
    }                                                                                          \
    _Pragma("unroll") for (int ni = 0; ni < 3; ++ni) {                                         \
      b0[ni] = *(const bf16x8*)(rB0 + (NB) + ni * 1024);                                       \
      b1[ni] = *(const bf16x8*)(rB1 + (NB) + ni * 1024);                                       \
    }                                                                                          \
    if (SGHI) {                                                                                \
      gload16(pA2, dA2 + ((NA) ^ 16384)); gload16(pA3, dA3 + ((NA) ^ 16384));                  \
      pA2 += 64; pA3 += 64;                                                                    \
      gload16(pB0, dB0 + ((NB) ^ 12288)); gload16(pB1, dB1 + ((NB) ^ 12288));                  \
      gload16(pB2, dB2 + ((NB) ^ 12288));                                                      \
      pB0 += 64; pB1 += 64; pB2 += 64;                                                         \
    }                                                                                          \
    __builtin_amdgcn_s_barrier();                                                              \
    __builtin_amdgcn_s_setprio(1);                                                             \
    MM24(0, a0, a1)                                                                            \
    __builtin_amdgcn_s_setprio(0);                                                             \
    __builtin_amdgcn_sched_barrier(0);                                                         \
    if (HASV0) vmwait<7>();                                                                    \
    __builtin_amdgcn_s_barrier();                                                              \
    _Pragma("unroll") for (int mi = 0; mi < 4; ++mi) {                                         \
      a0[mi] = *(const bf16x8*)(rA0 + (NA) + 8192 + mi * 1024);                                \
      a1[mi] = *(const bf16x8*)(rA1 + (NA) + 8192 + mi * 1024);                                \
    }                                                                                          \
    if (SGLO) {                                                                                \
      gload16(pA0, dA0 + (NA)); gload16(pA1, dA1 + (NA));                                      \
      pA0 += 64; pA1 += 64;                                                                    \
    }                                                                                          \
    __builtin_amdgcn_s_barrier();                                                              \
    __builtin_amdgcn_s_setprio(1);                                                             \
    MM24(1, a0, a1)                                                                            \
    __builtin_amdgcn_s_setprio(0);                                                             \
    __builtin_amdgcn_sched_barrier(0);                                                         \
    if (HASV1) vmwait<VM1>();                                                                  \
    __builtin_amdgcn_s_barrier();                                                              \
  }

__global__ __launch_bounds__(512, 2) void gemm192(const u16* __restrict__ A, const u16* __restrict__ Bt,
                                                  u16* __restrict__ C, int M, int N, int K) {
  __shared__ __align__(16) u16 sA[2 * 16384];   // 256 rows x 64, dbuf
  __shared__ __align__(16) u16 sB[2 * 12288];   // 192 rows x 64, dbuf
  const int nbx = N / 192;
  const int nwg = (M >> 8) * nbx;
  const int cpx = nwg >> 3;  // nwg % 8 == 0 (512)
  const int wg = ((int)blockIdx.x & 7) * cpx + ((int)blockIdx.x >> 3);
  const int row0 = (wg / nbx) << 8, col0 = (wg % nbx) * 192;
  const int tid = threadIdx.x, w = tid >> 6, lane = tid & 63;
  const int wm = w >> 2, wn = w & 3;
  const int lq = lane & 15, lh = lane >> 4, x7 = lq & 7;
  const int o0 = (lh ^ x7) << 3, o1 = ((4 + lh) ^ x7) << 3;
  const int nt = K >> 6;

  const int rr = tid >> 3;
  const int swz = ((tid & 7) ^ (rr & 7)) << 3;
  const u16* pA0 = A + (size_t)(row0 + rr) * K + swz;
  const u16* pA1 = A + (size_t)(row0 + 64 + rr) * K + swz;
  const u16* pA2 = A + (size_t)(row0 + 128 + rr) * K + swz;
  const u16* pA3 = A + (size_t)(row0 + 192 + rr) * K + swz;
  const u16* pB0 = Bt + (size_t)(col0 + rr) * K + swz;
  const u16* pB1 = Bt + (size_t)(col0 + 64 + rr) * K + swz;
  const u16* pB2 = Bt + (size_t)(col0 + 128 + rr) * K + swz;
  u16* dA0 = sA + w * 512;
  u16* dA1 = sA + 4096 + w * 512;
  u16* dA2 = sA + 8192 + w * 512;
  u16* dA3 = sA + 12288 + w * 512;
  u16* dB0 = sB + w * 512;
  u16* dB1 = sB + 4096 + w * 512;
  u16* dB2 = sB + 8192 + w * 512;
  const u16* rA0 = sA + (wm * 64 + lq) * 64 + o0;
  const u16* rA1 = sA + (wm * 64 + lq) * 64 + o1;
  const u16* rB0 = sB + (wn * 48 + lq) * 64 + o0;
  const u16* rB1 = sB + (wn * 48 + lq) * 64 + o1;

  f32x4 acc[2][4][3] = {};

  gload16(pA0, dA0); gload16(pA1, dA1); pA0 += 64; pA1 += 64;
  gload16(pB0, dB0); gload16(pB1, dB1); gload16(pB2, dB2); pB0 += 64; pB1 += 64; pB2 += 64;
  gload16(pA2, dA2); gload16(pA3, dA3); pA2 += 64; pA3 += 64;
  gload16(pA0, dA0 + 16384); gload16(pA1, dA1 + 16384); pA0 += 64; pA1 += 64;
  vmwait<4>();
  __builtin_amdgcn_s_barrier();

  for (int t = 0; t < nt - 2; t += 2) {
    KT192(0, 0, 1, 1, 1, 1, 2)
    KT192(16384, 12288, 1, 1, 1, 1, 2)
  }
  KT192(0, 0, 1, 0, 1, 1, 0)          // t = nt-2
  KT192(16384, 12288, 0, 0, 0, 0, 0)  // t = nt-1

#pragma unroll
  for (int ah = 0; ah < 2; ++ah)
#pragma unroll
    for (int mi = 0; mi < 4; ++mi)
#pragma unroll
      for (int ni = 0; ni < 3; ++ni)
#pragma unroll
        for (int j = 0; j < 4; ++j) {
          const int row = row0 + ah * 128 + wm * 64 + mi * 16 + lh * 4 + j;
          const int col = col0 + wn * 48 + ni * 16 + lq;
          C[(size_t)row * N + col] = f2b(acc[ah][mi][ni][j]);
        }
}

// ---------- fused RoPE (NeoX, vectorized) + V transpose (disjoint qkv sections) ----------
__global__ void rope_vt_kernel(u16* __restrict__ qkv, const int* __restrict__ pos, float qscale,
                               u16* __restrict__ vt) {
  const int tid = threadIdx.x;
  if (blockIdx.x < 4096) {
    // ---- RoPE on q/k sections (qkv cols 0..5119) ----
    __shared__ float cs[64], sn[64];
    const int row = blockIdx.x;
    if (tid < 64) {
      float p = (float)pos[row];
      float inv = exp2f(-(float)tid * 0.20762050593046f);
      float a = p * inv;
      cs[tid] = cosf(a);
      sn[tid] = sinf(a);
    }
    __syncthreads();
    const size_t base = (size_t)row * QKV_N;
    for (int i = tid; i < 40 * 16; i += 256) {  // 40 heads x 16 d-quads
      const int h = i >> 4, dq = (i & 15) * 4;
      const size_t o = base + h * 128 + dq;
      ushort4 v1 = *(const ushort4*)&qkv[o];
      ushort4 v2 = *(const ushort4*)&qkv[o + 64];
      const float sc = (h < NH) ? qscale : 1.0f;
      ushort4 r1, r2;
      {
        float x1 = b2f(v1.x), x2 = b2f(v2.x), c = cs[dq], s = sn[dq];
        r1.x = f2b((x1 * c - x2 * s) * sc); r2.x = f2b((x2 * c + x1 * s) * sc);
      }
      {
        float x1 = b2f(v1.y), x2 = b2f(v2.y), c = cs[dq + 1], s = sn[dq + 1];
        r1.y = f2b((x1 * c - x2 * s) * sc); r2.y = f2b((x2 * c + x1 * s) * sc);
      }
      {
        float x1 = b2f(v1.z), x2 = b2f(v2.z), c = cs[dq + 2], s = sn[dq + 2];
        r1.z = f2b((x1 * c - x2 * s) * sc); r2.z = f2b((x2 * c + x1 * s) * sc);
      }
      {
        float x1 = b2f(v1.w), x2 = b2f(v2.w), c = cs[dq + 3], s = sn[dq + 3];
        r1.w = f2b((x1 * c - x2 * s) * sc); r2.w = f2b((x2 * c + x1 * s) * sc);
      }
      *(ushort4*)&qkv[o] = r1;
      *(ushort4*)&qkv[o + 64] = r2;
    }
  } else {
    // ---- V transpose: qkv cols 5120..6143 -> vt[(b*8+kvh)*128 + d][2048] ----
    __shared__ u16 t[32][33];
    const int idx = blockIdx.x - 4096;     // old grid (64, 4, 16)
    const int sx = idx & 63, d0b = (idx >> 6) & 3, z = idx >> 8;
    const int b = z >> 3, kvh = z & 7;
    const int s0 = sx * 32, d0 = d0b * 32;
    const int tx = tid & 31, ty = tid >> 5;
#pragma unroll
    for (int i = 0; i < 4; ++i)
      t[ty + i * 8][tx] = qkv[(size_t)(b * SEQ + s0 + ty + i * 8) * QKV_N + 5120 + kvh * 128 + d0 + tx];
    __syncthreads();
#pragma unroll
    for (int i = 0; i < 4; ++i)
      vt[(size_t)((b * NKV + kvh) * HD + d0 + ty + i * 8) * SEQ + s0 + tx] = t[tx][ty + i * 8];
  }
}

// ---------------- Flash attention: 8 waves x 32 q-rows, 32x32x16 MFMA, swapped QK^T ----------------
__global__ __launch_bounds__(512, 2) void attn_kernel(const u16* __restrict__ qkv, const u16* __restrict__ vt,
                                                      u16* __restrict__ attn) {
  __shared__ __align__(16) u16 sK[2][64 * 128];   // [kv][d]
  __shared__ __align__(16) u16 sV[2][128 * 64];   // [d][kv]
  const int b = blockIdx.z, h = blockIdx.y;
  const int qt = (b == 0) ? blockIdx.x : 7 - blockIdx.x;  // anti-correlated pairing for balance
  const int kvh = h >> 2;
  const int qb = qt * 256;
  const int tid = threadIdx.x, w = tid >> 6, lane = tid & 63;
  const int lq = lane & 31, hi = lane >> 5, x7 = lane & 7;
  const int qw = qb + (w << 5);
  const int qa = qw + lq;
  const int nt = 4 * (qt + 1);

  auto stage = [&](int buf, int kt) {
    const int k0 = kt * 64;
#pragma unroll
    for (int c = 0; c < 2; ++c) {
      const int g = c * 512 + tid;
      const int r = g >> 4, gc = g & 15;
      const int gs = gc ^ (r & 7);
      gload16(qkv + (size_t)(b * SEQ + k0 + r) * QKV_N + 4096 + kvh * 128 + gs * 8,
              &sK[buf][(c * 512 + (w << 6)) * 8]);
    }
#pragma unroll
    for (int c = 0; c < 2; ++c) {
      const int g = c * 512 + tid;
      const int r = g >> 3, gc = g & 7;
      const int gs = gc ^ (r & 7);
      gload16(vt + (size_t)((b * NKV + kvh) * HD + r) * SEQ + k0 + gs * 8,
              &sV[buf][(c * 512 + (w << 6)) * 8]);
    }
  };

  stage(0, 0);
  bf16x8 qf[8];
#pragma unroll
  for (int ks = 0; ks < 8; ++ks)
    qf[ks] = *(const bf16x8*)&qkv[(size_t)(b * SEQ + qw + lq) * QKV_N + h * 128 + ks * 16 + 8 * hi];

  f32x16 o[4] = {};
  float mreg = -1e30f, lreg = 0.f;

  asm volatile("s_waitcnt vmcnt(0)" ::: "memory");
  __builtin_amdgcn_s_barrier();

  for (int kt = 0; kt < nt; ++kt) {
    const int cur = kt & 1;
    const int k0 = kt * 64;
    if (kt + 1 < nt) {
      stage(cur ^ 1, kt + 1);
      asm volatile("s_waitcnt vmcnt(4)" ::: "memory");
    } else {
      asm volatile("s_waitcnt vmcnt(0)" ::: "memory");
    }
    __builtin_amdgcn_s_barrier();

    if (k0 <= qw + 31) {  // wave-active (causal skip)
      const u16* sk = sK[cur];
      f32x16 st0 = {}, st1 = {};
      __builtin_amdgcn_s_setprio(1);
#pragma unroll
      for (int ks = 0; ks < 8; ++ks) {
        const int g = ((2 * ks + hi) ^ x7) * 8;
        bf16x8 kf0 = *(const bf16x8*)&sk[lq * 128 + g];
        bf16x8 kf1 = *(const bf16x8*)&sk[(32 + lq) * 128 + g];
        st0 = __builtin_amdgcn_mfma_f32_32x32x16_bf16(kf0, qf[ks], st0, 0, 0, 0);
        st1 = __builtin_amdgcn_mfma_f32_32x32x16_bf16(kf1, qf[ks], st1, 0, 0, 0);
      }
      __builtin_amdgcn_s_setprio(0);
      if (k0 + 63 > qw) {
#pragma unroll
        for (int r = 0; r < 16; ++r) {
          const int cr = (r & 3) + 8 * (r >> 2) + 4 * hi;
          st0[r] = (k0 + cr <= qa) ? st0[r] : -1e30f;
          st1[r] = (k0 + 32 + cr <= qa) ? st1[r] : -1e30f;
        }
      }
      float a8[8];
#pragma unroll
      for (int r = 0; r < 8; ++r)
        a8[r] = fmaxf(fmaxf(st0[r], st0[r + 8]), fmaxf(st1[r], st1[r + 8]));
#pragma unroll
      for (int s = 4; s; s >>= 1)
#pragma unroll
        for (int r = 0; r < s; ++r) a8[r] = fmaxf(a8[r], a8[r + s]);
      const float pm = pl_partner_max(a8[0]);
      if (!__all(pm <= mreg + 8.f)) {
        const float mn = fmaxf(mreg, pm);
        const float al = exp2f(mreg - mn);
        lreg *= al;
        mreg = mn;
#pragma unroll
        for (int r = 0; r < 16; ++r) {
          const int cr = (r & 3) + 8 * (r >> 2) + 4 * hi;
          const float ar = __shfl(al, cr, 64);
#pragma unroll
          for (int dn = 0; dn < 4; ++dn) o[dn][r] *= ar;
        }
      }
#pragma unroll
      for (int r = 0; r < 16; ++r) {
        st0[r] = exp2f(st0[r] - mreg);
        st1[r] = exp2f(st1[r] - mreg);
      }
      float s8[8];
#pragma unroll
      for (int r = 0; r < 8; ++r)
        s8[r] = (st0[r] + st0[r + 8]) + (st1[r] + st1[r + 8]);
#pragma unroll
      for (int s = 4; s; s >>= 1)
#pragma unroll
        for (int r = 0; r < s; ++r) s8[r] += s8[r + s];
      lreg += pl_partner_sum(s8[0]);
      union U8 { unsigned w[4]; bf16x8 v; };
      U8 pa[4];
#define PACKFRAG(F, P0, P1, P2, P3, P4, P5, P6, P7)                   \
      {                                                               \
        unsigned a0 = pk(P0, P1), a1 = pk(P2, P3);                    \
        unsigned b0 = pk(P4, P5), b1 = pk(P6, P7);                    \
        plswap(a0, b0); plswap(a1, b1);                               \
        pa[F].w[0] = a0; pa[F].w[1] = a1; pa[F].w[2] = b0; pa[F].w[3] = b1; \
      }
      PACKFRAG(0, st0[0], st0[1], st0[2], st0[3], st0[4], st0[5], st0[6], st0[7])
      PACKFRAG(1, st0[8], st0[9], st0[10], st0[11], st0[12], st0[13], st0[14], st0[15])
      PACKFRAG(2, st1[0], st1[1], st1[2], st1[3], st1[4], st1[5], st1[6], st1[7])
      PACKFRAG(3, st1[8], st1[9], st1[10], st1[11], st1[12], st1[13], st1[14], st1[15])
#undef PACKFRAG
      const u16* sv = sV[cur];
      __builtin_amdgcn_s_setprio(1);
#pragma unroll
      for (int dn = 0; dn < 4; ++dn) {
#pragma unroll
        for (int ks = 0; ks < 4; ++ks) {
          bf16x8 vf = *(const bf16x8*)&sv[(dn * 32 + lq) * 64 + (((2 * ks + hi) ^ x7)) * 8];
          o[dn] = __builtin_amdgcn_mfma_f32_32x32x16_bf16(pa[ks].v, vf, o[dn], 0, 0, 0);
        }
      }
      __builtin_amdgcn_s_setprio(0);
    }
    __builtin_amdgcn_s_barrier();
  }

  const float inv = 1.0f / lreg;
#pragma unroll
  for (int r = 0; r < 16; ++r) {
    const int cr = (r & 3) + 8 * (r >> 2) + 4 * hi;
    const float fr = __shfl(inv, cr, 64);
    const size_t row = (size_t)(b * SEQ + qw + cr);
#pragma unroll
    for (int dn = 0; dn < 4; ++dn)
      attn[row * 4096 + h * 128 + dn * 32 + lq] = f2b(o[dn][r] * fr);
  }
}

extern "C" void kernel_launch(void* const* d_in, const int* in_sizes, int n_in,
                              void* d_out, int out_size, void* d_ws, size_t ws_size,
                              hipStream_t stream) {
  const float* hs = (const float*)d_in[0];
  const int* pos = (const int*)d_in[1];
  const float* w_qkv = (const float*)d_in[2];
  const float* w_o = (const float*)d_in[3];
  float* out = (float*)d_out;
  char* ws = (char*)d_ws;

  u16* hid = (u16*)ws;                        // 4096*4096 bf16 = 32 MiB
  u16* attnb = hid;                           // reused after qkv GEMM consumes hid
  u16* wT = (u16*)(ws + 33554432);            // up to 6144*4096 bf16 = 48 MiB
  u16* qkv = (u16*)(ws + 83886080);           // 4096*6144 bf16 = 48 MiB
  u16* vt = (u16*)(ws + 134217728);           // 2*8*128*2048 bf16 = 8 MiB

  const float qscale = 0.12751744f;  // (1/sqrt(128)) * log2(e)

  cast_f32_bf16<<<16384, 256, 0, stream>>>(hs, hid, 4096 * 4096);
  cast_transpose<<<dim3(192, 128), dim3(32, 8), 0, stream>>>(w_qkv, wT, 4096, QKV_N);
  gemm192<<<512, 512, 0, stream>>>(hid, wT, qkv, 4096, QKV_N, 4096);
  rope_vt_kernel<<<8192, 256, 0, stream>>>(qkv, pos, qscale, vt);
  cast_transpose<<<dim3(128, 128), dim3(32, 8), 0, stream>>>(w_o, wT, 4096, 4096);
  attn_kernel<<<dim3(8, 32, 2), 512, 0, stream>>>(qkv, vt, attnb);
  gemm256<float><<<256, 512, 0, stream>>>(attnb, wT, out, 4096, 4096, 4096);
}

// Round 15
// 514.318 us; speedup vs baseline: 1.0573x; 1.0065x over previous
//
#include <hip/hip_runtime.h>
#include <hip/hip_bf16.h>
#include <stdint.h>
#include <stddef.h>

typedef unsigned short u16;
typedef __bf16 bf16x8 __attribute__((ext_vector_type(8)));
typedef float f32x4 __attribute__((ext_vector_type(4)));
typedef float f32x16 __attribute__((ext_vector_type(16)));
typedef unsigned u32x2 __attribute__((ext_vector_type(2)));

#define NH 32
#define NKV 8
#define HD 128
#define QKV_N 6144
#define SEQ 2048

__device__ __forceinline__ u16 f2b(float x) {
  union { float f; unsigned u; } v; v.f = x;
  unsigned r = v.u + 0x7FFF + ((v.u >> 16) & 1);
  return (u16)(r >> 16);
}
__device__ __forceinline__ float b2f(u16 b) {
  union { float f; unsigned u; } v; v.u = ((unsigned)b) << 16;
  return v.f;
}
__device__ __forceinline__ void gload16(const void* g, void* l) {
  __builtin_amdgcn_global_load_lds((const __attribute__((address_space(1))) unsigned int*)g,
                                   (__attribute__((address_space(3))) unsigned int*)l, 16, 0, 0);
}
template <int N>
__device__ __forceinline__ void vmwait() {
  asm volatile("s_waitcnt vmcnt(%0)" ::"n"(N) : "memory");
}
__device__ __forceinline__ unsigned pk(float lo, float hi) {
  union { __bf16 h[2]; unsigned w; } u;
  u.h[0] = (__bf16)lo; u.h[1] = (__bf16)hi;
  return u.w;
}
__device__ __forceinline__ void plswap(unsigned& a, unsigned& b) {
  u32x2 r = __builtin_amdgcn_permlane32_swap(a, b, false, false);
  a = r.x; b = r.y;
}
__device__ __forceinline__ float pl_partner_max(float x) {
  unsigned u = __float_as_uint(x);
  u32x2 r = __builtin_amdgcn_permlane32_swap(u, u, false, false);
  return fmaxf(__uint_as_float(r.x), __uint_as_float(r.y));
}
__device__ __forceinline__ float pl_partner_sum(float x) {
  unsigned u = __float_as_uint(x);
  u32x2 r = __builtin_amdgcn_permlane32_swap(u, u, false, false);
  return __uint_as_float(r.x) + __uint_as_float(r.y);
}

// ---------------- cast fp32 -> bf16 (vectorized) ----------------
__global__ void cast_f32_bf16(const float* __restrict__ in, u16* __restrict__ out, int n) {
  int i = (blockIdx.x * blockDim.x + threadIdx.x) * 4;
  if (i >= n) return;
  float4 v = *(const float4*)&in[i];
  ushort4 o;
  o.x = f2b(v.x); o.y = f2b(v.y); o.z = f2b(v.z); o.w = f2b(v.w);
  *(ushort4*)&out[i] = o;
}

// ---------- cast + transpose: in [K][N] fp32 -> out [N][K] bf16 ----------
__global__ void cast_transpose(const float* __restrict__ in, u16* __restrict__ out, int K, int N) {
  __shared__ float t[32][33];
  int n0 = blockIdx.x * 32, k0 = blockIdx.y * 32;
  int tx = threadIdx.x, ty = threadIdx.y;  // (32,8)
#pragma unroll
  for (int i = 0; i < 4; ++i)
    t[ty + i * 8][tx] = in[(size_t)(k0 + ty + i * 8) * N + n0 + tx];
  __syncthreads();
#pragma unroll
  for (int i = 0; i < 4; ++i)
    out[(size_t)(n0 + ty + i * 8) * K + k0 + tx] = f2b(t[tx][ty + i * 8]);
}

__device__ __forceinline__ void storeC(float* C, size_t i, float v) { C[i] = v; }
__device__ __forceinline__ void storeC(u16* C, size_t i, float v) { C[i] = f2b(v); }

// ======================= gemm256 (KT256 ladder; o-proj, 256 blocks = 1/CU) =======================
#define MFMA16(q, A0, A1, B0, B1)                                                              \
  {                                                                                            \
    _Pragma("unroll") for (int mi = 0; mi < 4; ++mi)                                           \
      _Pragma("unroll") for (int ni = 0; ni < 2; ++ni)                                         \
        acc[q][mi][ni] = __builtin_amdgcn_mfma_f32_16x16x32_bf16(A0[mi], B0[ni], acc[q][mi][ni], 0, 0, 0); \
    _Pragma("unroll") for (int mi = 0; mi < 4; ++mi)                                           \
      _Pragma("unroll") for (int ni = 0; ni < 2; ++ni)                                         \
        acc[q][mi][ni] = __builtin_amdgcn_mfma_f32_16x16x32_bf16(A1[mi], B1[ni], acc[q][mi][ni], 0, 0, 0); \
  }

#define KT256(NOFF, SGHI, SGLO, HASV0, HASV1, VM1)                                             \
  {                                                                                            \
    bf16x8 a0[4], a1[4], bl0[2], bl1[2], bh0[2], bh1[2];                                       \
    _Pragma("unroll") for (int mi = 0; mi < 4; ++mi) {                                         \
      a0[mi] = *(const bf16x8*)(rA0 + (NOFF) + mi * 1024);                                     \
      a1[mi] = *(const bf16x8*)(rA1 + (NOFF) + mi * 1024);                                     \
    }                                                                                          \
    _Pragma("unroll") for (int ni = 0; ni < 2; ++ni) {                                         \
      bl0[ni] = *(const bf16x8*)(rB0 + (NOFF) + ni * 1024);                                    \
      bl1[ni] = *(const bf16x8*)(rB1 + (NOFF) + ni * 1024);                                    \
      bh0[ni] = *(const bf16x8*)(rB0 + (NOFF) + 8192 + ni * 1024);                             \
      bh1[ni] = *(const bf16x8*)(rB1 + (NOFF) + 8192 + ni * 1024);                             \
    }                                                                                          \
    if (SGHI) {                                                                                \
      gload16(pAhi0, dAhi0 + ((NOFF) ^ 16384)); gload16(pAhi1, dAhi1 + ((NOFF) ^ 16384));      \
      pAhi0 += 64; pAhi1 += 64;                                                                \
      gload16(pBlo0, dBlo0 + ((NOFF) ^ 16384)); gload16(pBlo1, dBlo1 + ((NOFF) ^ 16384));      \
      gload16(pBhi0, dBhi0 + ((NOFF) ^ 16384)); gload16(pBhi1, dBhi1 + ((NOFF) ^ 16384));      \
      pBlo0 += 64; pBlo1 += 64; pBhi0 += 64; pBhi1 += 64;                                      \
    }                                                                                          \
    __builtin_amdgcn_s_barrier();                                                              \
    __builtin_amdgcn_s_setprio(1);                                                             \
    MFMA16(0, a0, a1, bl0, bl1)                                                                \
    MFMA16(1, a0, a1, bh0, bh1)                                                                \
    __builtin_amdgcn_s_setprio(0);                                                             \
    __builtin_amdgcn_sched_barrier(0);                                                         \
    if (HASV0) vmwait<8>();                                                                    \
    __builtin_amdgcn_s_barrier();                                                              \
    _Pragma("unroll") for (int mi = 0; mi < 4; ++mi) {                                         \
      a0[mi] = *(const bf16x8*)(rA0 + (NOFF) + 8192 + mi * 1024);                              \
      a1[mi] = *(const bf16x8*)(rA1 + (NOFF) + 8192 + mi * 1024);                              \
    }                                                                                          \
    if (SGLO) {                                                                                \
      gload16(pAlo0, dAlo0 + (NOFF)); gload16(pAlo1, dAlo1 + (NOFF));                          \
      pAlo0 += 64; pAlo1 += 64;                                                                \
    }                                                                                          \
    __builtin_amdgcn_s_barrier();                                                              \
    __builtin_amdgcn_s_setprio(1);                                                             \
    MFMA16(2, a0, a1, bl0, bl1)                                                                \
    MFMA16(3, a0, a1, bh0, bh1)                                                                \
    __builtin_amdgcn_s_setprio(0);                                                             \
    __builtin_amdgcn_sched_barrier(0);                                                         \
    if (HASV1) vmwait<VM1>();                                                                  \
    __builtin_amdgcn_s_barrier();                                                              \
  }

template <typename OutT>
__global__ __launch_bounds__(512, 2) void gemm256(const u16* __restrict__ A, const u16* __restrict__ Bt,
                                                  OutT* __restrict__ C, int M, int N, int K) {
  __shared__ __align__(16) u16 sA[2 * 16384];
  __shared__ __align__(16) u16 sB[2 * 16384];
  const int nbx = N >> 8;
  const int nwg = (M >> 8) * nbx;
  const int cpx = nwg >> 3;
  const int wg = ((int)blockIdx.x & 7) * cpx + ((int)blockIdx.x >> 3);
  const int row0 = (wg / nbx) << 8, col0 = (wg % nbx) << 8;
  const int tid = threadIdx.x, w = tid >> 6, lane = tid & 63;
  const int wm = w >> 2, wn = w & 3;
  const int lq = lane & 15, lh = lane >> 4, x7 = lq & 7;
  const int o0 = (lh ^ x7) << 3, o1 = ((4 + lh) ^ x7) << 3;
  const int nt = K >> 6;

  const int rr = tid >> 3;
  const int swz = ((tid & 7) ^ (rr & 7)) << 3;
  const u16* pAlo0 = A + (size_t)(row0 + rr) * K + swz;
  const u16* pAlo1 = A + (size_t)(row0 + 64 + rr) * K + swz;
  const u16* pAhi0 = A + (size_t)(row0 + 128 + rr) * K + swz;
  const u16* pAhi1 = A + (size_t)(row0 + 192 + rr) * K + swz;
  const u16* pBlo0 = Bt + (size_t)(col0 + rr) * K + swz;
  const u16* pBlo1 = Bt + (size_t)(col0 + 64 + rr) * K + swz;
  const u16* pBhi0 = Bt + (size_t)(col0 + 128 + rr) * K + swz;
  const u16* pBhi1 = Bt + (size_t)(col0 + 192 + rr) * K + swz;
  u16* dAlo0 = sA + w * 512;
  u16* dAlo1 = sA + 4096 + w * 512;
  u16* dAhi0 = sA + 8192 + w * 512;
  u16* dAhi1 = sA + 12288 + w * 512;
  u16* dBlo0 = sB + w * 512;
  u16* dBlo1 = sB + 4096 + w * 512;
  u16* dBhi0 = sB + 8192 + w * 512;
  u16* dBhi1 = sB + 12288 + w * 512;
  const u16* rA0 = sA + (wm * 64 + lq) * 64 + o0;
  const u16* rA1 = sA + (wm * 64 + lq) * 64 + o1;
  const u16* rB0 = sB + (wn * 32 + lq) * 64 + o0;
  const u16* rB1 = sB + (wn * 32 + lq) * 64 + o1;

  f32x4 acc[4][4][2] = {};

  gload16(pAlo0, dAlo0); gload16(pAlo1, dAlo1); pAlo0 += 64; pAlo1 += 64;
  gload16(pBlo0, dBlo0); gload16(pBlo1, dBlo1); pBlo0 += 64; pBlo1 += 64;
  gload16(pBhi0, dBhi0); gload16(pBhi1, dBhi1); pBhi0 += 64; pBhi1 += 64;
  gload16(pAhi0, dAhi0); gload16(pAhi1, dAhi1); pAhi0 += 64; pAhi1 += 64;
  gload16(pAlo0, dAlo0 + 16384); gload16(pAlo1, dAlo1 + 16384); pAlo0 += 64; pAlo1 += 64;
  vmwait<4>();  // A-lo(0), B(0) landed; leaves [A-hi(0)2, A-lo(1)2]
  __builtin_amdgcn_s_barrier();

  for (int t = 0; t < nt - 2; t += 2) {
    KT256(0, 1, 1, 1, 1, 2)
    KT256(16384, 1, 1, 1, 1, 2)
  }
  KT256(0, 1, 0, 1, 1, 0)      // t = nt-2
  KT256(16384, 0, 0, 0, 0, 0)  // t = nt-1

#pragma unroll
  for (int q = 0; q < 4; ++q) {
    const int ah = q >> 1, bh2 = q & 1;
#pragma unroll
    for (int mi = 0; mi < 4; ++mi)
#pragma unroll
      for (int ni = 0; ni < 2; ++ni)
#pragma unroll
        for (int j = 0; j < 4; ++j) {
          const int row = row0 + ah * 128 + wm * 64 + mi * 16 + lh * 4 + j;
          const int col = col0 + bh2 * 128 + wn * 32 + ni * 16 + lq;
          storeC(C, (size_t)row * N + col, acc[q][mi][ni][j]);
        }
  }
}

// ===== gemm192: BM=256, BN=192, dbuf; 4x2 wave grid (per-wave 64 rows x 96 cols, 20 b128/tile) =====
// P0: read A ks0+ks1 for own 64 rows (8 b128) + B ks0 (6); stage A-hi(t+1)+B(t+1)->nxt;
//     BAR; 24 MFMA ks0; vm7; BAR.
// P1: read B ks1 (6); stage A-lo(t+2)->cur; BAR; 24 MFMA ks1; vm2; BAR.
// FIFO: entering t outstanding = [Alo(t+1)2]; ALL of tile t's data landed (vm2 at P1(t-1)
// drains Alo(t+1-1=t)... precisely: P1(t-1) end vm2 leaves only Alo(t+1); so A(t),B(t) landed). 
// Prologue: issue A(0)4, B(0)3, Alo(1)2 -> vm2 leaves [Alo(1)2]. Tail t=nt-2: vm0; t=nt-1: none.
// WAR: SGLO(t) overwrites cur A-lo rows, last read P0(t), 1 barrier earlier (proven skeleton
// argument: reads complete before reading wave passes P0-end barrier; stage issues after).
// SGHI targets nxt buf (not read this tile).
#define MM24B(A2, B2)                                                                          \
  _Pragma("unroll") for (int mi = 0; mi < 4; ++mi)                                             \
    _Pragma("unroll") for (int ni = 0; ni < 6; ++ni)                                           \
      acc[mi][ni] = __builtin_amdgcn_mfma_f32_16x16x32_bf16(A2[mi], B2[ni], acc[mi][ni], 0, 0, 0);

#define KT192(NA, NB, SGHI, SGLO, HASV0, HASV1, VM1)                                           \
  {                                                                                            \
    bf16x8 a0[4], a1[4], b0[6], b1[6];                                                         \
    _Pragma("unroll") for (int mi = 0; mi < 4; ++mi) {                                         \
      a0[mi] = *(const bf16x8*)(rA0 + (NA) + mi * 1024);                                       \
      a1[mi] = *(const bf16x8*)(rA1 + (NA) + mi * 1024);                                       \
    }                                                                                          \
    _Pragma("unroll") for (int ni = 0; ni < 6; ++ni)                                           \
      b0[ni] = *(const bf16x8*)(rB0 + (NB) + ni * 1024);                                       \
    if (SGHI) {                                                                                \
      gload16(pA2, dA2 + ((NA) ^ 16384)); gload16(pA3, dA3 + ((NA) ^ 16384));                  \
      pA2 += 64; pA3 += 64;                                                                    \
      gload16(pB0, dB0 + ((NB) ^ 12288)); gload16(pB1, dB1 + ((NB) ^ 12288));                  \
      gload16(pB2, dB2 + ((NB) ^ 12288));                                                      \
      pB0 += 64; pB1 += 64; pB2 += 64;                                                         \
    }                                                                                          \
    __builtin_amdgcn_s_barrier();                                                              \
    __builtin_amdgcn_s_setprio(1);                                                             \
    MM24B(a0, b0)                                                                              \
    __builtin_amdgcn_s_setprio(0);                                                             \
    __builtin_amdgcn_sched_barrier(0);                                                         \
    if (HASV0) vmwait<7>();                                                                    \
    __builtin_amdgcn_s_barrier();                                                              \
    _Pragma("unroll") for (int ni = 0; ni < 6; ++ni)                                           \
      b1[ni] = *(const bf16x8*)(rB1 + (NB) + ni * 1024);                                       \
    if (SGLO) {                                                                                \
      gload16(pA0, dA0 + (NA)); gload16(pA1, dA1 + (NA));                                      \
      pA0 += 64; pA1 += 64;                                                                    \
    }                                                                                          \
    __builtin_amdgcn_s_barrier();                                                              \
    __builtin_amdgcn_s_setprio(1);                                                             \
    MM24B(a1, b1)                                                                              \
    __builtin_amdgcn_s_setprio(0);                                                             \
    __builtin_amdgcn_sched_barrier(0);                                                         \
    if (HASV1) vmwait<VM1>();                                                                  \
    __builtin_amdgcn_s_barrier();                                                              \
  }

__global__ __launch_bounds__(512, 2) void gemm192(const u16* __restrict__ A, const u16* __restrict__ Bt,
                                                  u16* __restrict__ C, int M, int N, int K) {
  __shared__ __align__(16) u16 sA[2 * 16384];   // 256 rows x 64, dbuf
  __shared__ __align__(16) u16 sB[2 * 12288];   // 192 rows x 64, dbuf
  const int nbx = N / 192;
  const int nwg = (M >> 8) * nbx;
  const int cpx = nwg >> 3;  // nwg % 8 == 0 (512)
  const int wg = ((int)blockIdx.x & 7) * cpx + ((int)blockIdx.x >> 3);
  const int row0 = (wg / nbx) << 8, col0 = (wg % nbx) * 192;
  const int tid = threadIdx.x, w = tid >> 6, lane = tid & 63;
  const int wm = w >> 1, wn = w & 1;  // 4x2 wave grid
  const int lq = lane & 15, lh = lane >> 4, x7 = lq & 7;
  const int o0 = (lh ^ x7) << 3, o1 = ((4 + lh) ^ x7) << 3;
  const int nt = K >> 6;

  const int rr = tid >> 3;
  const int swz = ((tid & 7) ^ (rr & 7)) << 3;
  const u16* pA0 = A + (size_t)(row0 + rr) * K + swz;
  const u16* pA1 = A + (size_t)(row0 + 64 + rr) * K + swz;
  const u16* pA2 = A + (size_t)(row0 + 128 + rr) * K + swz;
  const u16* pA3 = A + (size_t)(row0 + 192 + rr) * K + swz;
  const u16* pB0 = Bt + (size_t)(col0 + rr) * K + swz;
  const u16* pB1 = Bt + (size_t)(col0 + 64 + rr) * K + swz;
  const u16* pB2 = Bt + (size_t)(col0 + 128 + rr) * K + swz;
  u16* dA0 = sA + w * 512;
  u16* dA1 = sA + 4096 + w * 512;
  u16* dA2 = sA + 8192 + w * 512;
  u16* dA3 = sA + 12288 + w * 512;
  u16* dB0 = sB + w * 512;
  u16* dB1 = sB + 4096 + w * 512;
  u16* dB2 = sB + 8192 + w * 512;
  const u16* rA0 = sA + (wm * 64 + lq) * 64 + o0;
  const u16* rA1 = sA + (wm * 64 + lq) * 64 + o1;
  const u16* rB0 = sB + (wn * 96 + lq) * 64 + o0;
  const u16* rB1 = sB + (wn * 96 + lq) * 64 + o1;

  f32x4 acc[4][6] = {};

  // prologue: A(0)4, B(0)3, Alo(1)2; vm2 -> all of tile 0 landed, leaves [Alo(1)2]
  gload16(pA0, dA0); gload16(pA1, dA1); pA0 += 64; pA1 += 64;
  gload16(pB0, dB0); gload16(pB1, dB1); gload16(pB2, dB2); pB0 += 64; pB1 += 64; pB2 += 64;
  gload16(pA2, dA2); gload16(pA3, dA3); pA2 += 64; pA3 += 64;
  gload16(pA0, dA0 + 16384); gload16(pA1, dA1 + 16384); pA0 += 64; pA1 += 64;
  vmwait<2>();
  __builtin_amdgcn_s_barrier();

  for (int t = 0; t < nt - 2; t += 2) {
    KT192(0, 0, 1, 1, 1, 1, 2)
    KT192(16384, 12288, 1, 1, 1, 1, 2)
  }
  KT192(0, 0, 1, 0, 1, 1, 0)          // t = nt-2
  KT192(16384, 12288, 0, 0, 0, 0, 0)  // t = nt-1

#pragma unroll
  for (int mi = 0; mi < 4; ++mi)
#pragma unroll
    for (int ni = 0; ni < 6; ++ni)
#pragma unroll
      for (int j = 0; j < 4; ++j) {
        const int row = row0 + wm * 64 + mi * 16 + lh * 4 + j;
        const int col = col0 + wn * 96 + ni * 16 + lq;
        C[(size_t)row * N + col] = f2b(acc[mi][ni][j]);
      }
}

// ---------- fused RoPE (NeoX, vectorized) + V transpose (disjoint qkv sections) ----------
__global__ void rope_vt_kernel(u16* __restrict__ qkv, const int* __restrict__ pos, float qscale,
                               u16* __restrict__ vt) {
  const int tid = threadIdx.x;
  if (blockIdx.x < 4096) {
    __shared__ float cs[64], sn[64];
    const int row = blockIdx.x;
    if (tid < 64) {
      float p = (float)pos[row];
      float inv = exp2f(-(float)tid * 0.20762050593046f);
      float a = p * inv;
      cs[tid] = cosf(a);
      sn[tid] = sinf(a);
    }
    __syncthreads();
    const size_t base = (size_t)row * QKV_N;
    for (int i = tid; i < 40 * 16; i += 256) {
      const int h = i >> 4, dq = (i & 15) * 4;
      const size_t o = base + h * 128 + dq;
      ushort4 v1 = *(const ushort4*)&qkv[o];
      ushort4 v2 = *(const ushort4*)&qkv[o + 64];
      const float sc = (h < NH) ? qscale : 1.0f;
      ushort4 r1, r2;
      {
        float x1 = b2f(v1.x), x2 = b2f(v2.x), c = cs[dq], s = sn[dq];
        r1.x = f2b((x1 * c - x2 * s) * sc); r2.x = f2b((x2 * c + x1 * s) * sc);
      }
      {
        float x1 = b2f(v1.y), x2 = b2f(v2.y), c = cs[dq + 1], s = sn[dq + 1];
        r1.y = f2b((x1 * c - x2 * s) * sc); r2.y = f2b((x2 * c + x1 * s) * sc);
      }
      {
        float x1 = b2f(v1.z), x2 = b2f(v2.z), c = cs[dq + 2], s = sn[dq + 2];
        r1.z = f2b((x1 * c - x2 * s) * sc); r2.z = f2b((x2 * c + x1 * s) * sc);
      }
      {
        float x1 = b2f(v1.w), x2 = b2f(v2.w), c = cs[dq + 3], s = sn[dq + 3];
        r1.w = f2b((x1 * c - x2 * s) * sc); r2.w = f2b((x2 * c + x1 * s) * sc);
      }
      *(ushort4*)&qkv[o] = r1;
      *(ushort4*)&qkv[o + 64] = r2;
    }
  } else {
    __shared__ u16 t[32][33];
    const int idx = blockIdx.x - 4096;
    const int sx = idx & 63, d0b = (idx >> 6) & 3, z = idx >> 8;
    const int b = z >> 3, kvh = z & 7;
    const int s0 = sx * 32, d0 = d0b * 32;
    const int tx = tid & 31, ty = tid >> 5;
#pragma unroll
    for (int i = 0; i < 4; ++i)
      t[ty + i * 8][tx] = qkv[(size_t)(b * SEQ + s0 + ty + i * 8) * QKV_N + 5120 + kvh * 128 + d0 + tx];
    __syncthreads();
#pragma unroll
    for (int i = 0; i < 4; ++i)
      vt[(size_t)((b * NKV + kvh) * HD + d0 + ty + i * 8) * SEQ + s0 + tx] = t[tx][ty + i * 8];
  }
}

// ---------------- Flash attention: 8 waves x 32 q-rows, 32x32x16 MFMA, swapped QK^T ----------------
__global__ __launch_bounds__(512, 2) void attn_kernel(const u16* __restrict__ qkv, const u16* __restrict__ vt,
                                                      u16* __restrict__ attn) {
  __shared__ __align__(16) u16 sK[2][64 * 128];   // [kv][d]
  __shared__ __align__(16) u16 sV[2][128 * 64];   // [d][kv]
  const int b = blockIdx.z, h = blockIdx.y;
  const int qt = (b == 0) ? blockIdx.x : 7 - blockIdx.x;
  const int kvh = h >> 2;
  const int qb = qt * 256;
  const int tid = threadIdx.x, w = tid >> 6, lane = tid & 63;
  const int lq = lane & 31, hi = lane >> 5, x7 = lane & 7;
  const int qw = qb + (w << 5);
  const int qa = qw + lq;
  const int nt = 4 * (qt + 1);

  auto stage = [&](int buf, int kt) {
    const int k0 = kt * 64;
#pragma unroll
    for (int c = 0; c < 2; ++c) {
      const int g = c * 512 + tid;
      const int r = g >> 4, gc = g & 15;
      const int gs = gc ^ (r & 7);
      gload16(qkv + (size_t)(b * SEQ + k0 + r) * QKV_N + 4096 + kvh * 128 + gs * 8,
              &sK[buf][(c * 512 + (w << 6)) * 8]);
    }
#pragma unroll
    for (int c = 0; c < 2; ++c) {
      const int g = c * 512 + tid;
      const int r = g >> 3, gc = g & 7;
      const int gs = gc ^ (r & 7);
      gload16(vt + (size_t)((b * NKV + kvh) * HD + r) * SEQ + k0 + gs * 8,
              &sV[buf][(c * 512 + (w << 6)) * 8]);
    }
  };

  stage(0, 0);
  bf16x8 qf[8];
#pragma unroll
  for (int ks = 0; ks < 8; ++ks)
    qf[ks] = *(const bf16x8*)&qkv[(size_t)(b * SEQ + qw + lq) * QKV_N + h * 128 + ks * 16 + 8 * hi];

  f32x16 o[4] = {};
  float mreg = -1e30f, lreg = 0.f;

  asm volatile("s_waitcnt vmcnt(0)" ::: "memory");
  __builtin_amdgcn_s_barrier();

  for (int kt = 0; kt < nt; ++kt) {
    const int cur = kt & 1;
    const int k0 = kt * 64;
    if (kt + 1 < nt) {
      stage(cur ^ 1, kt + 1);
      asm volatile("s_waitcnt vmcnt(4)" ::: "memory");
    } else {
      asm volatile("s_waitcnt vmcnt(0)" ::: "memory");
    }
    __builtin_amdgcn_s_barrier();

    if (k0 <= qw + 31) {
      const u16* sk = sK[cur];
      f32x16 st0 = {}, st1 = {};
      __builtin_amdgcn_s_setprio(1);
#pragma unroll
      for (int ks = 0; ks < 8; ++ks) {
        const int g = ((2 * ks + hi) ^ x7) * 8;
        bf16x8 kf0 = *(const bf16x8*)&sk[lq * 128 + g];
        bf16x8 kf1 = *(const bf16x8*)&sk[(32 + lq) * 128 + g];
        st0 = __builtin_amdgcn_mfma_f32_32x32x16_bf16(kf0, qf[ks], st0, 0, 0, 0);
        st1 = __builtin_amdgcn_mfma_f32_32x32x16_bf16(kf1, qf[ks], st1, 0, 0, 0);
      }
      __builtin_amdgcn_s_setprio(0);
      if (k0 + 63 > qw) {
#pragma unroll
        for (int r = 0; r < 16; ++r) {
          const int cr = (r & 3) + 8 * (r >> 2) + 4 * hi;
          st0[r] = (k0 + cr <= qa) ? st0[r] : -1e30f;
          st1[r] = (k0 + 32 + cr <= qa) ? st1[r] : -1e30f;
        }
      }
      float a8[8];
#pragma unroll
      for (int r = 0; r < 8; ++r)
        a8[r] = fmaxf(fmaxf(st0[r], st0[r + 8]), fmaxf(st1[r], st1[r + 8]));
#pragma unroll
      for (int s = 4; s; s >>= 1)
#pragma unroll
        for (int r = 0; r < s; ++r) a8[r] = fmaxf(a8[r], a8[r + s]);
      const float pm = pl_partner_max(a8[0]);
      if (!__all(pm <= mreg + 8.f)) {
        const float mn = fmaxf(mreg, pm);
        const float al = exp2f(mreg - mn);
        lreg *= al;
        mreg = mn;
#pragma unroll
        for (int r = 0; r < 16; ++r) {
          const int cr = (r & 3) + 8 * (r >> 2) + 4 * hi;
          const float ar = __shfl(al, cr, 64);
#pragma unroll
          for (int dn = 0; dn < 4; ++dn) o[dn][r] *= ar;
        }
      }
#pragma unroll
      for (int r = 0; r < 16; ++r) {
        st0[r] = exp2f(st0[r] - mreg);
        st1[r] = exp2f(st1[r] - mreg);
      }
      float s8[8];
#pragma unroll
      for (int r = 0; r < 8; ++r)
        s8[r] = (st0[r] + st0[r + 8]) + (st1[r] + st1[r + 8]);
#pragma unroll
      for (int s = 4; s; s >>= 1)
#pragma unroll
        for (int r = 0; r < s; ++r) s8[r] += s8[r + s];
      lreg += pl_partner_sum(s8[0]);
      union U8 { unsigned w[4]; bf16x8 v; };
      U8 pa[4];
#define PACKFRAG(F, P0, P1, P2, P3, P4, P5, P6, P7)                   \
      {                                                               \
        unsigned a0 = pk(P0, P1), a1 = pk(P2, P3);                    \
        unsigned b0 = pk(P4, P5), b1 = pk(P6, P7);                    \
        plswap(a0, b0); plswap(a1, b1);                               \
        pa[F].w[0] = a0; pa[F].w[1] = a1; pa[F].w[2] = b0; pa[F].w[3] = b1; \
      }
      PACKFRAG(0, st0[0], st0[1], st0[2], st0[3], st0[4], st0[5], st0[6], st0[7])
      PACKFRAG(1, st0[8], st0[9], st0[10], st0[11], st0[12], st0[13], st0[14], st0[15])
      PACKFRAG(2, st1[0], st1[1], st1[2], st1[3], st1[4], st1[5], st1[6], st1[7])
      PACKFRAG(3, st1[8], st1[9], st1[10], st1[11], st1[12], st1[13], st1[14], st1[15])
#undef PACKFRAG
      const u16* sv = sV[cur];
      __builtin_amdgcn_s_setprio(1);
#pragma unroll
      for (int dn = 0; dn < 4; ++dn) {
#pragma unroll
        for (int ks = 0; ks < 4; ++ks) {
          bf16x8 vf = *(const bf16x8*)&sv[(dn * 32 + lq) * 64 + (((2 * ks + hi) ^ x7)) * 8];
          o[dn] = __builtin_amdgcn_mfma_f32_32x32x16_bf16(pa[ks].v, vf, o[dn], 0, 0, 0);
        }
      }
      __builtin_amdgcn_s_setprio(0);
    }
    __builtin_amdgcn_s_barrier();
  }

  const float inv = 1.0f / lreg;
#pragma unroll
  for (int r = 0; r < 16; ++r) {
    const int cr = (r & 3) + 8 * (r >> 2) + 4 * hi;
    const float fr = __shfl(inv, cr, 64);
    const size_t row = (size_t)(b * SEQ + qw + cr);
#pragma unroll
    for (int dn = 0; dn < 4; ++dn)
      attn[row * 4096 + h * 128 + dn * 32 + lq] = f2b(o[dn][r] * fr);
  }
}

extern "C" void kernel_launch(void* const* d_in, const int* in_sizes, int n_in,
                              void* d_out, int out_size, void* d_ws, size_t ws_size,
                              hipStream_t stream) {
  const float* hs = (const float*)d_in[0];
  const int* pos = (const int*)d_in[1];
  const float* w_qkv = (const float*)d_in[2];
  const float* w_o = (const float*)d_in[3];
  float* out = (float*)d_out;
  char* ws = (char*)d_ws;

  u16* hid = (u16*)ws;                        // 4096*4096 bf16 = 32 MiB
  u16* attnb = hid;                           // reused after qkv GEMM consumes hid
  u16* wT = (u16*)(ws + 33554432);            // up to 6144*4096 bf16 = 48 MiB
  u16* qkv = (u16*)(ws + 83886080);           // 4096*6144 bf16 = 48 MiB
  u16* vt = (u16*)(ws + 134217728);           // 2*8*128*2048 bf16 = 8 MiB

  const float qscale = 0.12751744f;  // (1/sqrt(128)) * log2(e)

  cast_f32_bf16<<<16384, 256, 0, stream>>>(hs, hid, 4096 * 4096);
  cast_transpose<<<dim3(192, 128), dim3(32, 8), 0, stream>>>(w_qkv, wT, 4096, QKV_N);
  gemm192<<<512, 512, 0, stream>>>(hid, wT, qkv, 4096, QKV_N, 4096);
  rope_vt_kernel<<<8192, 256, 0, stream>>>(qkv, pos, qscale, vt);
  cast_transpose<<<dim3(128, 128), dim3(32, 8), 0, stream>>>(w_o, wT, 4096, 4096);
  attn_kernel<<<dim3(8, 32, 2), 512, 0, stream>>>(qkv, vt, attnb);
  gemm256<float><<<256, 512, 0, stream>>>(attnb, wT, out, 4096, 4096, 4096);
}